// Round 9
// baseline (419.061 us; speedup 1.0000x reference)
//
#include <hip/hip_runtime.h>

typedef unsigned short u16;
typedef unsigned int u32;
typedef __attribute__((ext_vector_type(8))) short short8;
typedef __attribute__((ext_vector_type(4))) float float4v;

#define LDS_S 136   // padded row stride (bf16 elems) for Wt
#define RS 8192     // node-range size (32KB LDS int counters)
#define RSH 13
#define GP 8        // partition chunks per col-chunk

__device__ inline float bf16_lo(u32 v) { return __uint_as_float(v << 16); }
__device__ inline float bf16_hi(u32 v) { return __uint_as_float(v & 0xFFFF0000u); }

__device__ inline u16 f32_to_bf16(float f) {
    u32 u = __float_as_uint(f);
    u32 r = u + 0x7FFFu + ((u >> 16) & 1u);   // round-to-nearest-even
    return (u16)(r >> 16);
}

// ---------------- P0: partition edges by col-range (pairs) and src-range (srcp) -------------
__global__ __launch_bounds__(256) void partition_kernel(const int* __restrict__ er,
                                                        const int* __restrict__ ec,
                                                        u32* __restrict__ pairs,
                                                        u16* __restrict__ srcp,
                                                        int* __restrict__ rof,
                                                        int* __restrict__ srof,
                                                        int E, int cpb, int NR) {
    __shared__ int cnt[16], scnt[16];
    const int k = blockIdx.x, tid = threadIdx.x;
    const int e0 = k * cpb, e1 = min(e0 + cpb, E);
    if (tid < 16) { cnt[tid] = 0; scnt[tid] = 0; }
    __syncthreads();
    for (int e = e0 + tid; e < e1; e += 256) {
        atomicAdd(&cnt[ec[e] >> RSH], 1);
        atomicAdd(&scnt[er[e] >> RSH], 1);
    }
    __syncthreads();
    if (tid == 0) {
        int run = 0;
        for (int r = 0; r < NR; r++) { int c = cnt[r]; rof[k*16 + r] = run; cnt[r] = run; run += c; }
        rof[k*16 + NR] = run;
        run = 0;
        for (int r = 0; r < NR; r++) { int c = scnt[r]; srof[k*16 + r] = run; scnt[r] = run; run += c; }
        srof[k*16 + NR] = run;
    }
    __syncthreads();
    const size_t base = (size_t)k * cpb;
    for (int e = e0 + tid; e < e1; e += 256) {
        int s = er[e], c = ec[e];
        int slot = atomicAdd(&cnt[c >> RSH], 1);
        pairs[base + slot] = ((u32)s << 16) | (u32)c;
        int slot2 = atomicAdd(&scnt[s >> RSH], 1);
        srcp[base + slot2] = (u16)s;
    }
}

// ---------------- col histogram over partitioned pairs -> pcol u16 --------------------------
__global__ __launch_bounds__(256) void colhist_kernel(const u32* __restrict__ pairs,
                                                      const int* __restrict__ rof,
                                                      u16* __restrict__ pcol,
                                                      int N, int cpb) {
    __shared__ alignas(16) int hist[RS];
    const int kc = blockIdx.x, r = blockIdx.y, tid = threadIdx.x;
    const int rbase = r << RSH;
    const int rcount = min(RS, N - rbase);
    for (int j = tid; j < RS / 4; j += 256) ((int4*)hist)[j] = make_int4(0, 0, 0, 0);
    __syncthreads();
    for (int g = 0; g < GP; g++) {
        const int kp = kc * GP + g;
        const size_t base = (size_t)kp * cpb;
        const int s = rof[kp*16 + r], e = rof[kp*16 + r + 1];
        for (int i = s + tid; i < e; i += 256) {
            u32 p = pairs[base + i];
            atomicAdd(&hist[(int)(p & 0xFFFFu) - rbase], 1);
        }
    }
    __syncthreads();
    for (int j = tid; j < rcount; j += 256)
        pcol[(size_t)kc * N + rbase + j] = (u16)hist[j];
}

// ---------------- deg histogram over partitioned srcs -> pdeg u16 ---------------------------
__global__ __launch_bounds__(256) void deghist_kernel(const u16* __restrict__ srcp,
                                                      const int* __restrict__ srof,
                                                      u16* __restrict__ pdeg,
                                                      int N, int cpb, int GPD) {
    __shared__ alignas(16) int hist[RS];
    const int kd = blockIdx.x, r = blockIdx.y, tid = threadIdx.x;
    const int rbase = r << RSH;
    const int rcount = min(RS, N - rbase);
    for (int j = tid; j < RS / 4; j += 256) ((int4*)hist)[j] = make_int4(0, 0, 0, 0);
    __syncthreads();
    for (int g = 0; g < GPD; g++) {
        const int kp = kd * GPD + g;
        const size_t base = (size_t)kp * cpb;
        const int s = srof[kp*16 + r], e = srof[kp*16 + r + 1];
        for (int i = s + tid; i < e; i += 256)
            atomicAdd(&hist[(int)srcp[base + i] - rbase], 1);
    }
    __syncthreads();
    for (int j = tid; j < rcount; j += 256)
        pdeg[(size_t)kd * N + rbase + j] = (u16)hist[j];
}

// ---------------- chunk scan (pcol) + phase-A block reduce + dis (fused) --------------------
__global__ __launch_bounds__(256) void chunk_scan_kernel(u16* __restrict__ pcol,
                                                         const u16* __restrict__ pdeg,
                                                         int* __restrict__ totals,
                                                         int* __restrict__ bsum,
                                                         float* __restrict__ dis,
                                                         int N, int NC, int NCD) {
    __shared__ int red[256];
    int i = blockIdx.x * 256 + threadIdx.x;
    int pre = 0;
    if (i < N) {
        for (int k = 0; k < NC; k++) {
            size_t p = (size_t)k * N + i;
            int v = pcol[p];
            pcol[p] = (u16)pre;
            pre += v;
        }
        totals[i] = pre;
        int s = 0;
        for (int k = 0; k < NCD; k++) s += pdeg[(size_t)k * N + i];
        dis[i] = rsqrtf((float)(s + 1));  // +1 self loop; always > 0
    }
    red[threadIdx.x] = pre;
    __syncthreads();
#pragma unroll
    for (int off = 128; off > 0; off >>= 1) {
        if (threadIdx.x < off) red[threadIdx.x] += red[threadIdx.x + off];
        __syncthreads();
    }
    if (threadIdx.x == 0) bsum[blockIdx.x] = red[0];
}

// Phase B: single-block exclusive scan over nblk block sums (nblk <= 1024).
__global__ __launch_bounds__(1024) void scan_bsum_kernel(int* __restrict__ bsum, int nblk) {
    __shared__ int part[1024];
    int tid = threadIdx.x;
    int v = (tid < nblk) ? bsum[tid] : 0;
    part[tid] = v;
    __syncthreads();
    for (int off = 1; off < 1024; off <<= 1) {
        int t = (tid >= off) ? part[tid - off] : 0;
        __syncthreads();
        part[tid] += t;
        __syncthreads();
    }
    if (tid < nblk) bsum[tid] = part[tid] - v;   // exclusive
}

// Phase C: rowptr[i] = bsum[b] + block-exclusive-scan(tot); rowptr[N] = E.
__global__ __launch_bounds__(256) void rowptr_kernel(const int* __restrict__ totals,
                                                     const int* __restrict__ bsum,
                                                     int* __restrict__ rowptr, int N, int E) {
    __shared__ int part[256];
    int tid = threadIdx.x;
    int i = blockIdx.x * 256 + tid;
    int v = (i < N) ? totals[i] : 0;
    part[tid] = v;
    __syncthreads();
    for (int off = 1; off < 256; off <<= 1) {
        int t = (tid >= off) ? part[tid - off] : 0;
        __syncthreads();
        part[tid] += t;
        __syncthreads();
    }
    if (i < N) rowptr[i] = bsum[blockIdx.x] + part[tid] - v;
    if (i == 0) rowptr[N] = E;
}

// ---------------- CSR fill from partitioned pairs; per-edge base gathers; u16 csr -----------
__global__ __launch_bounds__(256) void fill_kernel(const u32* __restrict__ pairs,
                                                   const int* __restrict__ rof,
                                                   const int* __restrict__ rowptr,
                                                   const u16* __restrict__ pcol,
                                                   u16* __restrict__ csr,
                                                   int N, int cpb) {
    __shared__ alignas(16) int hist[RS];
    const int kc = blockIdx.x, r = blockIdx.y, tid = threadIdx.x;
    const int rbase = r << RSH;
    for (int j = tid; j < RS / 4; j += 256) ((int4*)hist)[j] = make_int4(0, 0, 0, 0);
    __syncthreads();
    for (int g = 0; g < GP; g++) {
        const int kp = kc * GP + g;
        const size_t base = (size_t)kp * cpb;
        const int s = rof[kp*16 + r], e = rof[kp*16 + r + 1];
        for (int i = s + tid; i < e; i += 256) {
            u32 p = pairs[base + i];
            int c = (int)(p & 0xFFFFu);
            int src = (int)(p >> 16);
            int loc = atomicAdd(&hist[c - rbase], 1);
            int pos = rowptr[c] + (int)pcol[(size_t)kc * N + c] + loc;
            csr[pos] = (u16)src;
        }
    }
}

// ---------------- dense transform: H' = dis .* (X @ W), quarter-banked output ----------------
// H layout: hq[q][node][32] (u16), q = channel>>5 — each quarter table is contiguous (3.2MB)
// so a channel-quarter agg pass has an L2-resident working set.
__global__ __launch_bounds__(256) void gemm_xw(const float* __restrict__ X,
                                               const float* __restrict__ W,
                                               const float* __restrict__ dis,
                                               u16* __restrict__ H, int M) {
    __shared__ u16 Wt[128 * LDS_S];  // Wt[n][k] = bf16(W[k][n]), padded stride
    const int tid = threadIdx.x;
    for (int idx = tid; idx < 128 * 128; idx += 256) {
        int k = idx >> 7, nn = idx & 127;
        Wt[nn * LDS_S + k] = f32_to_bf16(W[idx]);
    }
    __syncthreads();

    const int lane = tid & 63, wave = tid >> 6;
    const int quad = lane >> 4, r = lane & 15;
    int arow = blockIdx.x * 64 + wave * 16 + r;        // A-operand row (m = lane&15)
    if (arow >= M) arow = M - 1;
    const float* xrow = X + (size_t)arow * 128;

    float4v acc[8];
#pragma unroll
    for (int i = 0; i < 8; i++) acc[i] = (float4v)(0.0f);

#pragma unroll
    for (int kk = 0; kk < 4; kk++) {
        const int k0 = kk * 32 + quad * 8;             // a[j] = A[m][k0+j]
        float4 x0 = *(const float4*)(xrow + k0);
        float4 x1 = *(const float4*)(xrow + k0 + 4);
        short8 a;
        a[0] = (short)f32_to_bf16(x0.x); a[1] = (short)f32_to_bf16(x0.y);
        a[2] = (short)f32_to_bf16(x0.z); a[3] = (short)f32_to_bf16(x0.w);
        a[4] = (short)f32_to_bf16(x1.x); a[5] = (short)f32_to_bf16(x1.y);
        a[6] = (short)f32_to_bf16(x1.z); a[7] = (short)f32_to_bf16(x1.w);
#pragma unroll
        for (int nt = 0; nt < 8; nt++) {
            short8 b = *(const short8*)(&Wt[(nt * 16 + r) * LDS_S + k0]);
            acc[nt] = __builtin_amdgcn_mfma_f32_16x16x32_bf16(a, b, acc[nt], 0, 0, 0);
        }
    }

    // C/D layout: col = lane&15 (=r), row-in-tile = quad*4 + reg
    const int orow0 = blockIdx.x * 64 + wave * 16 + quad * 4;
#pragma unroll
    for (int reg = 0; reg < 4; reg++) {
        int gr = orow0 + reg;
        if (gr < M) {
            float dscale = dis[gr];
#pragma unroll
            for (int nt = 0; nt < 8; nt++) {
                // channel c = nt*16 + r  -> quarter q = nt>>1, offset (nt&1)*16 + r
                u16* hp = H + (size_t)(nt >> 1) * M * 32 + (size_t)gr * 32 + (nt & 1) * 16 + r;
                *hp = f32_to_bf16(dscale * acc[nt][reg]);
            }
        }
    }
}

// ---------------- quarter aggregation: out[i, q*32:(q+1)*32] ---------------------------------
// One wave per node. 4 lanes per 64B row-slice; lane-group g = lane>>2 handles edges
// j%16==g -> one dwordx4 gathers 16 rows/wave-instruction from the 3.2MB quarter table.
// All __shfl wave-uniform (R7 lesson: shfl from exec-masked lane is undefined).
__global__ __launch_bounds__(256) void agg_q_kernel(const u16* __restrict__ hq,
                                                    const float* __restrict__ dis,
                                                    const int* __restrict__ rowptr,
                                                    const u16* __restrict__ csr,
                                                    const float* __restrict__ bias,
                                                    float* __restrict__ out,
                                                    int N, int do_relu, int q) {
    const int wave = threadIdx.x >> 6, lane = threadIdx.x & 63;
    const int node = blockIdx.x * 4 + wave;
    if (node >= N) return;
    const int grp = lane >> 2;        // edge phase 0..15
    const int sub = lane & 3;         // 16B slice of the 64B row

    float acc[8];
#pragma unroll
    for (int i = 0; i < 8; i++) acc[i] = 0.0f;

    int e = rowptr[node];
    const int end = rowptr[node + 1];
    while (e < end) {
        const int nb = min(64, end - e);
        int s = (int)csr[min(e + lane, end - 1)];   // coalesced batch of up to 64 src ids
        int j0 = 0;
        for (; j0 + 16 <= nb; j0 += 16) {
            int j = j0 + grp;
            int sj = __shfl(s, j);
            uint4 v = *(const uint4*)(hq + (size_t)sj * 32 + sub * 8);
            acc[0] += bf16_lo(v.x); acc[1] += bf16_hi(v.x);
            acc[2] += bf16_lo(v.y); acc[3] += bf16_hi(v.y);
            acc[4] += bf16_lo(v.z); acc[5] += bf16_hi(v.z);
            acc[6] += bf16_lo(v.w); acc[7] += bf16_hi(v.w);
        }
        for (; j0 < nb; j0 += 16) {
            int j = j0 + grp;                        // j <= 63 always
            int sj = __shfl(s, j);                   // UNIFORM
            if (j < nb) {
                uint4 v = *(const uint4*)(hq + (size_t)sj * 32 + sub * 8);
                acc[0] += bf16_lo(v.x); acc[1] += bf16_hi(v.x);
                acc[2] += bf16_lo(v.y); acc[3] += bf16_hi(v.y);
                acc[4] += bf16_lo(v.z); acc[5] += bf16_hi(v.z);
                acc[6] += bf16_lo(v.w); acc[7] += bf16_hi(v.w);
            }
        }
        e += nb;
    }

    // merge the 16 edge-phase groups (same channel slice every 4 lanes)
#pragma unroll
    for (int i = 0; i < 8; i++) {
        acc[i] += __shfl_xor(acc[i], 4);
        acc[i] += __shfl_xor(acc[i], 8);
        acc[i] += __shfl_xor(acc[i], 16);
        acc[i] += __shfl_xor(acc[i], 32);
    }

    if (grp == 0) {   // lanes 0-3 finalize + store 32 contiguous f32 channels
        const float di = dis[node];
        uint4 vs = *(const uint4*)(hq + (size_t)node * 32 + sub * 8);
        const float* bq = bias + q * 32 + sub * 8;
        float4 b0 = *(const float4*)bq;
        float4 b1 = *(const float4*)(bq + 4);
        float r0 = di * (acc[0] + bf16_lo(vs.x)) + b0.x;
        float r1 = di * (acc[1] + bf16_hi(vs.x)) + b0.y;
        float r2 = di * (acc[2] + bf16_lo(vs.y)) + b0.z;
        float r3 = di * (acc[3] + bf16_hi(vs.y)) + b0.w;
        float r4 = di * (acc[4] + bf16_lo(vs.z)) + b1.x;
        float r5 = di * (acc[5] + bf16_hi(vs.z)) + b1.y;
        float r6 = di * (acc[6] + bf16_lo(vs.w)) + b1.z;
        float r7 = di * (acc[7] + bf16_hi(vs.w)) + b1.w;
        if (do_relu) {
            r0 = fmaxf(r0, 0.0f); r1 = fmaxf(r1, 0.0f); r2 = fmaxf(r2, 0.0f); r3 = fmaxf(r3, 0.0f);
            r4 = fmaxf(r4, 0.0f); r5 = fmaxf(r5, 0.0f); r6 = fmaxf(r6, 0.0f); r7 = fmaxf(r7, 0.0f);
        }
        float* op = out + (size_t)node * 128 + q * 32 + sub * 8;
        *(float4*)op = make_float4(r0, r1, r2, r3);
        *(float4*)(op + 4) = make_float4(r4, r5, r6, r7);
    }
}

// ---------------- launch ----------------

extern "C" void kernel_launch(void* const* d_in, const int* in_sizes, int n_in,
                              void* d_out, int out_size, void* d_ws, size_t ws_size,
                              hipStream_t stream) {
    const float* x  = (const float*)d_in[0];   // [N,128] f32
    const int*   ei = (const int*)d_in[1];     // [2,E] int32
    const float* W1 = (const float*)d_in[2];   // [128,128] f32
    const float* b1 = (const float*)d_in[3];   // [128] f32
    const float* W2 = (const float*)d_in[4];
    const float* b2 = (const float*)d_in[5];
    float* out = (float*)d_out;                // [N,128] f32

    const int N = in_sizes[0] / 128;
    const int E = in_sizes[1] / 2;
    const int* er = ei;        // sources (gathered)
    const int* ec = ei + E;    // destinations (scattered)

    char* ws = (char*)d_ws;
    size_t off = 0;
    auto alloc = [&](size_t b) { size_t o = off; off += (b + 255) & ~(size_t)255; return o; };
    size_t o_tot  = alloc((size_t)N * 4);
    size_t o_rp   = alloc((size_t)(N + 1) * 4);
    size_t o_dis  = alloc((size_t)N * 4);
    size_t o_bsum = alloc((size_t)1024 * 4);
    size_t o_rof  = alloc((size_t)1024 * 16 * 4);
    size_t o_srof = alloc((size_t)1024 * 16 * 4);
    size_t o_csr  = alloc((size_t)E * 2);
    size_t o_h    = alloc((size_t)N * 128 * 2);
    size_t o_prs  = alloc((size_t)(E + 1024) * 4);
    size_t o_srcp = alloc((size_t)(E + 1024) * 2);

    size_t rem = (ws_size > off + 4096) ? (ws_size - off - 4096) : 0;
    long long nc = (long long)(rem / (3 * (size_t)N));
    if (nc > 128) nc = 128;
    if (nc < 16) nc = 16;
    nc &= ~1LL;
    const int NC = (int)nc, NCD = NC / 2;
    const int NCP = NC * GP;                 // partition chunks
    const int GPD = NCP / NCD;               // = 16

    size_t o_pcol = alloc((size_t)NC * N * 2);
    size_t o_pdeg = alloc((size_t)NCD * N * 2);

    int*   tot  = (int*)(ws + o_tot);
    int*   rp   = (int*)(ws + o_rp);
    float* dis  = (float*)(ws + o_dis);
    int*   bsum = (int*)(ws + o_bsum);
    int*   rof  = (int*)(ws + o_rof);
    int*   srof = (int*)(ws + o_srof);
    u16*   csr  = (u16*)(ws + o_csr);
    u16*   h    = (u16*)(ws + o_h);
    u32*   prs  = (u32*)(ws + o_prs);
    u16*   srcp = (u16*)(ws + o_srcp);
    u16*   pcol = (u16*)(ws + o_pcol);
    u16*   pdeg = (u16*)(ws + o_pdeg);

    const int NR = (N + RS - 1) / RS;        // 7 for N=50000 (must be <= 15)
    const int cpb  = (E + NCP - 1) / NCP;
    const int nblk = (N + 255) / 256;        // 196 (<= 1024 required)
    const int ablk = (N + 3) / 4;

    partition_kernel<<<NCP, 256, 0, stream>>>(er, ec, prs, srcp, rof, srof, E, cpb, NR);
    colhist_kernel<<<dim3(NC, NR), 256, 0, stream>>>(prs, rof, pcol, N, cpb);
    deghist_kernel<<<dim3(NCD, NR), 256, 0, stream>>>(srcp, srof, pdeg, N, cpb, GPD);
    chunk_scan_kernel<<<nblk, 256, 0, stream>>>(pcol, pdeg, tot, bsum, dis, N, NC, NCD);
    scan_bsum_kernel<<<1, 1024, 0, stream>>>(bsum, nblk);
    rowptr_kernel<<<nblk, 256, 0, stream>>>(tot, bsum, rp, N, E);
    fill_kernel<<<dim3(NC, NR), 256, 0, stream>>>(prs, rof, rp, pcol, csr, N, cpb);

    // layer 1: h' = dis.*bf16(x@W1), quarter-banked ; d_out = relu(agg(h') + b1)
    gemm_xw<<<(N + 63) / 64, 256, 0, stream>>>(x, W1, dis, h, N);
    for (int q = 0; q < 4; q++)
        agg_q_kernel<<<ablk, 256, 0, stream>>>(h + (size_t)q * N * 32, dis, rp, csr, b1, out, N, 1, q);

    // layer 2: h' = dis.*bf16(d_out@W2) ; d_out = agg(h') + b2
    gemm_xw<<<(N + 63) / 64, 256, 0, stream>>>(out, W2, dis, h, N);
    for (int q = 0; q < 4; q++)
        agg_q_kernel<<<ablk, 256, 0, stream>>>(h + (size_t)q * N * 32, dis, rp, csr, b2, out, N, 0, q);
}

// Round 10
// 293.200 us; speedup vs baseline: 1.4293x; 1.4293x over previous
//
#include <hip/hip_runtime.h>

typedef unsigned short u16;
typedef unsigned int u32;
typedef __attribute__((ext_vector_type(8))) short short8;
typedef __attribute__((ext_vector_type(4))) float float4v;

#define LDS_S 136   // padded row stride (bf16 elems) for Wt
#define RS 8192     // node-range size (32KB LDS int counters)
#define RSH 13
#define GP 8        // partition chunks per col-chunk

__device__ inline float bf16_lo(u32 v) { return __uint_as_float(v << 16); }
__device__ inline float bf16_hi(u32 v) { return __uint_as_float(v & 0xFFFF0000u); }

__device__ inline u16 f32_to_bf16(float f) {
    u32 u = __float_as_uint(f);
    u32 r = u + 0x7FFFu + ((u >> 16) & 1u);   // round-to-nearest-even
    return (u16)(r >> 16);
}

// ---------------- P0: partition edges by col-range (pairs) and src-range (srcp) -------------
__global__ __launch_bounds__(256) void partition_kernel(const int* __restrict__ er,
                                                        const int* __restrict__ ec,
                                                        u32* __restrict__ pairs,
                                                        u16* __restrict__ srcp,
                                                        int* __restrict__ rof,
                                                        int* __restrict__ srof,
                                                        int E, int cpb, int NR) {
    __shared__ int cnt[16], scnt[16];
    const int k = blockIdx.x, tid = threadIdx.x;
    const int e0 = k * cpb, e1 = min(e0 + cpb, E);
    if (tid < 16) { cnt[tid] = 0; scnt[tid] = 0; }
    __syncthreads();
    for (int e = e0 + tid; e < e1; e += 256) {
        atomicAdd(&cnt[ec[e] >> RSH], 1);
        atomicAdd(&scnt[er[e] >> RSH], 1);
    }
    __syncthreads();
    if (tid == 0) {
        int run = 0;
        for (int r = 0; r < NR; r++) { int c = cnt[r]; rof[k*16 + r] = run; cnt[r] = run; run += c; }
        rof[k*16 + NR] = run;
        run = 0;
        for (int r = 0; r < NR; r++) { int c = scnt[r]; srof[k*16 + r] = run; scnt[r] = run; run += c; }
        srof[k*16 + NR] = run;
    }
    __syncthreads();
    const size_t base = (size_t)k * cpb;
    for (int e = e0 + tid; e < e1; e += 256) {
        int s = er[e], c = ec[e];
        int slot = atomicAdd(&cnt[c >> RSH], 1);
        pairs[base + slot] = ((u32)s << 16) | (u32)c;
        int slot2 = atomicAdd(&scnt[s >> RSH], 1);
        srcp[base + slot2] = (u16)s;
    }
}

// ---------------- col histogram over partitioned pairs -> pcol u16 --------------------------
__global__ __launch_bounds__(256) void colhist_kernel(const u32* __restrict__ pairs,
                                                      const int* __restrict__ rof,
                                                      u16* __restrict__ pcol,
                                                      int N, int cpb) {
    __shared__ alignas(16) int hist[RS];
    const int kc = blockIdx.x, r = blockIdx.y, tid = threadIdx.x;
    const int rbase = r << RSH;
    const int rcount = min(RS, N - rbase);
    for (int j = tid; j < RS / 4; j += 256) ((int4*)hist)[j] = make_int4(0, 0, 0, 0);
    __syncthreads();
    for (int g = 0; g < GP; g++) {
        const int kp = kc * GP + g;
        const size_t base = (size_t)kp * cpb;
        const int s = rof[kp*16 + r], e = rof[kp*16 + r + 1];
        for (int i = s + tid; i < e; i += 256) {
            u32 p = pairs[base + i];
            atomicAdd(&hist[(int)(p & 0xFFFFu) - rbase], 1);
        }
    }
    __syncthreads();
    for (int j = tid; j < rcount; j += 256)
        pcol[(size_t)kc * N + rbase + j] = (u16)hist[j];
}

// ---------------- deg histogram over partitioned srcs -> pdeg u16 ---------------------------
__global__ __launch_bounds__(256) void deghist_kernel(const u16* __restrict__ srcp,
                                                      const int* __restrict__ srof,
                                                      u16* __restrict__ pdeg,
                                                      int N, int cpb, int GPD) {
    __shared__ alignas(16) int hist[RS];
    const int kd = blockIdx.x, r = blockIdx.y, tid = threadIdx.x;
    const int rbase = r << RSH;
    const int rcount = min(RS, N - rbase);
    for (int j = tid; j < RS / 4; j += 256) ((int4*)hist)[j] = make_int4(0, 0, 0, 0);
    __syncthreads();
    for (int g = 0; g < GPD; g++) {
        const int kp = kd * GPD + g;
        const size_t base = (size_t)kp * cpb;
        const int s = srof[kp*16 + r], e = srof[kp*16 + r + 1];
        for (int i = s + tid; i < e; i += 256)
            atomicAdd(&hist[(int)srcp[base + i] - rbase], 1);
    }
    __syncthreads();
    for (int j = tid; j < rcount; j += 256)
        pdeg[(size_t)kd * N + rbase + j] = (u16)hist[j];
}

// ---------------- chunk scan: 8 threads/node, register-batched loads + shfl prefix ----------
// R9's version was latency-bound (196 blocks, 128-long serialized load/store chain on pcol).
// Here: 400k threads, <=16 independent loads per thread, 3-step shfl_up prefix over 8 lanes.
__global__ __launch_bounds__(256) void chunk_scan_kernel(u16* __restrict__ pcol,
                                                         const u16* __restrict__ pdeg,
                                                         int* __restrict__ totals,
                                                         float* __restrict__ dis,
                                                         int N, int NC, int NCD) {
    const int gid = blockIdx.x * 256 + threadIdx.x;
    const int node = gid >> 3;
    const int t = threadIdx.x & 7;
    if (node >= N) return;
    const int per = NC >> 3;     // <= 16 (NC multiple of 16)
    const int k0 = t * per;
    int vals[16];
    int sum = 0;
#pragma unroll
    for (int j = 0; j < 16; j++) {      // independent guarded loads -> one latency round trip
        int v = 0;
        if (j < per) v = pcol[(size_t)(k0 + j) * N + node];
        vals[j] = v;
        sum += v;
    }
    int inc = sum;                       // inclusive scan across the node's 8 lanes
#pragma unroll
    for (int d = 1; d < 8; d <<= 1) {
        int v = __shfl_up(inc, d, 8);    // wave-uniform; sources within same 8-group
        if (t >= d) inc += v;
    }
    int run = inc - sum;                 // exclusive base for this thread's chunk span
#pragma unroll
    for (int j = 0; j < 16; j++) {
        if (j < per) {
            pcol[(size_t)(k0 + j) * N + node] = (u16)run;
            run += vals[j];
        }
    }
    if (t == 7) totals[node] = inc;      // lane 7's inclusive = node total

    const int perd = NCD >> 3;           // <= 8 (NCD multiple of 8)
    int s = 0;
#pragma unroll
    for (int j = 0; j < 8; j++) {
        if (j < perd) s += pdeg[(size_t)(t * perd + j) * N + node];
    }
    s += __shfl_xor(s, 1);
    s += __shfl_xor(s, 2);
    s += __shfl_xor(s, 4);
    if (t == 0) dis[node] = rsqrtf((float)(s + 1));  // +1 self loop; always > 0
}

// Phase A': per-256-node block sums of totals.
__global__ __launch_bounds__(256) void bsum_kernel(const int* __restrict__ totals,
                                                   int* __restrict__ bsum, int N) {
    __shared__ int red[256];
    int i = blockIdx.x * 256 + threadIdx.x;
    red[threadIdx.x] = (i < N) ? totals[i] : 0;
    __syncthreads();
#pragma unroll
    for (int off = 128; off > 0; off >>= 1) {
        if (threadIdx.x < off) red[threadIdx.x] += red[threadIdx.x + off];
        __syncthreads();
    }
    if (threadIdx.x == 0) bsum[blockIdx.x] = red[0];
}

// Phase B: single-block exclusive scan over nblk block sums (nblk <= 1024).
__global__ __launch_bounds__(1024) void scan_bsum_kernel(int* __restrict__ bsum, int nblk) {
    __shared__ int part[1024];
    int tid = threadIdx.x;
    int v = (tid < nblk) ? bsum[tid] : 0;
    part[tid] = v;
    __syncthreads();
    for (int off = 1; off < 1024; off <<= 1) {
        int t = (tid >= off) ? part[tid - off] : 0;
        __syncthreads();
        part[tid] += t;
        __syncthreads();
    }
    if (tid < nblk) bsum[tid] = part[tid] - v;   // exclusive
}

// Phase C: rowptr[i] = bsum[b] + block-exclusive-scan(tot); rowptr[N] = E.
__global__ __launch_bounds__(256) void rowptr_kernel(const int* __restrict__ totals,
                                                     const int* __restrict__ bsum,
                                                     int* __restrict__ rowptr, int N, int E) {
    __shared__ int part[256];
    int tid = threadIdx.x;
    int i = blockIdx.x * 256 + tid;
    int v = (i < N) ? totals[i] : 0;
    part[tid] = v;
    __syncthreads();
    for (int off = 1; off < 256; off <<= 1) {
        int t = (tid >= off) ? part[tid - off] : 0;
        __syncthreads();
        part[tid] += t;
        __syncthreads();
    }
    if (i < N) rowptr[i] = bsum[blockIdx.x] + part[tid] - v;
    if (i == 0) rowptr[N] = E;
}

// ---------------- CSR fill from partitioned pairs; per-edge base gathers; u16 csr -----------
__global__ __launch_bounds__(256) void fill_kernel(const u32* __restrict__ pairs,
                                                   const int* __restrict__ rof,
                                                   const int* __restrict__ rowptr,
                                                   const u16* __restrict__ pcol,
                                                   u16* __restrict__ csr,
                                                   int N, int cpb) {
    __shared__ alignas(16) int hist[RS];
    const int kc = blockIdx.x, r = blockIdx.y, tid = threadIdx.x;
    const int rbase = r << RSH;
    for (int j = tid; j < RS / 4; j += 256) ((int4*)hist)[j] = make_int4(0, 0, 0, 0);
    __syncthreads();
    for (int g = 0; g < GP; g++) {
        const int kp = kc * GP + g;
        const size_t base = (size_t)kp * cpb;
        const int s = rof[kp*16 + r], e = rof[kp*16 + r + 1];
        for (int i = s + tid; i < e; i += 256) {
            u32 p = pairs[base + i];
            int c = (int)(p & 0xFFFFu);
            int src = (int)(p >> 16);
            int loc = atomicAdd(&hist[c - rbase], 1);
            int pos = rowptr[c] + (int)pcol[(size_t)kc * N + c] + loc;
            csr[pos] = (u16)src;
        }
    }
}

// ---------------- dense transform: H' = dis .* (X @ W)  (f32 in, bf16 MFMA, bf16 out) --------
__global__ __launch_bounds__(256) void gemm_xw(const float* __restrict__ X,
                                               const float* __restrict__ W,
                                               const float* __restrict__ dis,
                                               u16* __restrict__ H, int M) {
    __shared__ u16 Wt[128 * LDS_S];  // Wt[n][k] = bf16(W[k][n]), padded stride
    const int tid = threadIdx.x;
    for (int idx = tid; idx < 128 * 128; idx += 256) {
        int k = idx >> 7, nn = idx & 127;
        Wt[nn * LDS_S + k] = f32_to_bf16(W[idx]);
    }
    __syncthreads();

    const int lane = tid & 63, wave = tid >> 6;
    const int quad = lane >> 4, r = lane & 15;
    int arow = blockIdx.x * 64 + wave * 16 + r;        // A-operand row (m = lane&15)
    if (arow >= M) arow = M - 1;
    const float* xrow = X + (size_t)arow * 128;

    float4v acc[8];
#pragma unroll
    for (int i = 0; i < 8; i++) acc[i] = (float4v)(0.0f);

#pragma unroll
    for (int kk = 0; kk < 4; kk++) {
        const int k0 = kk * 32 + quad * 8;             // a[j] = A[m][k0+j]
        float4 x0 = *(const float4*)(xrow + k0);
        float4 x1 = *(const float4*)(xrow + k0 + 4);
        short8 a;
        a[0] = (short)f32_to_bf16(x0.x); a[1] = (short)f32_to_bf16(x0.y);
        a[2] = (short)f32_to_bf16(x0.z); a[3] = (short)f32_to_bf16(x0.w);
        a[4] = (short)f32_to_bf16(x1.x); a[5] = (short)f32_to_bf16(x1.y);
        a[6] = (short)f32_to_bf16(x1.z); a[7] = (short)f32_to_bf16(x1.w);
#pragma unroll
        for (int nt = 0; nt < 8; nt++) {
            short8 b = *(const short8*)(&Wt[(nt * 16 + r) * LDS_S + k0]);
            acc[nt] = __builtin_amdgcn_mfma_f32_16x16x32_bf16(a, b, acc[nt], 0, 0, 0);
        }
    }

    // C/D layout: col = lane&15 (=r), row-in-tile = quad*4 + reg
    const int orow0 = blockIdx.x * 64 + wave * 16 + quad * 4;
#pragma unroll
    for (int reg = 0; reg < 4; reg++) {
        int gr = orow0 + reg;
        if (gr < M) {
            float dscale = dis[gr];
            u16* hp = H + (size_t)gr * 128 + r;
#pragma unroll
            for (int nt = 0; nt < 8; nt++) hp[nt * 16] = f32_to_bf16(dscale * acc[nt][reg]);
        }
    }
}

// ---------------- aggregation: out[i] = dis[i]*(sum h'[src] + h'[i]) + b --------------------
// One wave per node. Lane-group g (=lane>>4) handles edges j%4==g; each lane loads 16B
// (8 channels) of the 256B row -> one dwordx4 gathers 4 rows per wave-instruction.
// All __shfl wave-uniform (R7 lesson: shfl from exec-masked lane is undefined).
__global__ __launch_bounds__(256) void agg_kernel(const u16* __restrict__ h,
                                                  const float* __restrict__ dis,
                                                  const int* __restrict__ rowptr,
                                                  const u16* __restrict__ csr,
                                                  const float* __restrict__ bias,
                                                  float* __restrict__ out,
                                                  int N, int do_relu) {
    const int wave = threadIdx.x >> 6, lane = threadIdx.x & 63;
    const int node = blockIdx.x * 4 + wave;
    if (node >= N) return;
    const int grp = lane >> 4;        // edge phase 0..3
    const int sub = lane & 15;        // channels sub*8 .. sub*8+7

    float acc[8];
#pragma unroll
    for (int i = 0; i < 8; i++) acc[i] = 0.0f;

    int e = rowptr[node];
    const int end = rowptr[node + 1];
    while (e < end) {
        const int nb = min(64, end - e);
        int s = (int)csr[min(e + lane, end - 1)];   // coalesced batch of up to 64 src ids
        int j0 = 0;
        for (; j0 + 8 <= nb; j0 += 8) {             // 2 independent 4-row gathers in flight
            int ja = j0 + grp, jb = j0 + 4 + grp;
            int sa = __shfl(s, ja), sb = __shfl(s, jb);
            uint4 va = *(const uint4*)(h + (size_t)sa * 128 + sub * 8);
            uint4 vb = *(const uint4*)(h + (size_t)sb * 128 + sub * 8);
            acc[0] += bf16_lo(va.x) + bf16_lo(vb.x);
            acc[1] += bf16_hi(va.x) + bf16_hi(vb.x);
            acc[2] += bf16_lo(va.y) + bf16_lo(vb.y);
            acc[3] += bf16_hi(va.y) + bf16_hi(vb.y);
            acc[4] += bf16_lo(va.z) + bf16_lo(vb.z);
            acc[5] += bf16_hi(va.z) + bf16_hi(vb.z);
            acc[6] += bf16_lo(va.w) + bf16_lo(vb.w);
            acc[7] += bf16_hi(va.w) + bf16_hi(vb.w);
        }
        for (; j0 < nb; j0 += 4) {
            int j = j0 + grp;                        // j <= 63 always
            int sj = __shfl(s, j);                   // UNIFORM: every lane executes this
            if (j < nb) {                            // divergence only around load+accum
                uint4 v = *(const uint4*)(h + (size_t)sj * 128 + sub * 8);
                acc[0] += bf16_lo(v.x); acc[1] += bf16_hi(v.x);
                acc[2] += bf16_lo(v.y); acc[3] += bf16_hi(v.y);
                acc[4] += bf16_lo(v.z); acc[5] += bf16_hi(v.z);
                acc[6] += bf16_lo(v.w); acc[7] += bf16_hi(v.w);
            }
        }
        e += nb;
    }

    // merge the 4 edge-phase groups (all cover the same channel set)
#pragma unroll
    for (int i = 0; i < 8; i++) {
        acc[i] += __shfl_xor(acc[i], 16);
        acc[i] += __shfl_xor(acc[i], 32);
    }

    if (grp == 0) {   // lanes 0-15 finalize + store the 512B f32 row
        const float di = dis[node];
        uint4 vs = *(const uint4*)(h + (size_t)node * 128 + sub * 8);
        float4 b0 = *(const float4*)(bias + sub * 8);
        float4 b1 = *(const float4*)(bias + sub * 8 + 4);
        float r0 = di * (acc[0] + bf16_lo(vs.x)) + b0.x;
        float r1 = di * (acc[1] + bf16_hi(vs.x)) + b0.y;
        float r2 = di * (acc[2] + bf16_lo(vs.y)) + b0.z;
        float r3 = di * (acc[3] + bf16_hi(vs.y)) + b0.w;
        float r4 = di * (acc[4] + bf16_lo(vs.z)) + b1.x;
        float r5 = di * (acc[5] + bf16_hi(vs.z)) + b1.y;
        float r6 = di * (acc[6] + bf16_lo(vs.w)) + b1.z;
        float r7 = di * (acc[7] + bf16_hi(vs.w)) + b1.w;
        if (do_relu) {
            r0 = fmaxf(r0, 0.0f); r1 = fmaxf(r1, 0.0f); r2 = fmaxf(r2, 0.0f); r3 = fmaxf(r3, 0.0f);
            r4 = fmaxf(r4, 0.0f); r5 = fmaxf(r5, 0.0f); r6 = fmaxf(r6, 0.0f); r7 = fmaxf(r7, 0.0f);
        }
        float* op = out + (size_t)node * 128 + sub * 8;
        *(float4*)op = make_float4(r0, r1, r2, r3);
        *(float4*)(op + 4) = make_float4(r4, r5, r6, r7);
    }
}

// ---------------- launch ----------------

extern "C" void kernel_launch(void* const* d_in, const int* in_sizes, int n_in,
                              void* d_out, int out_size, void* d_ws, size_t ws_size,
                              hipStream_t stream) {
    const float* x  = (const float*)d_in[0];   // [N,128] f32
    const int*   ei = (const int*)d_in[1];     // [2,E] int32
    const float* W1 = (const float*)d_in[2];   // [128,128] f32
    const float* b1 = (const float*)d_in[3];   // [128] f32
    const float* W2 = (const float*)d_in[4];
    const float* b2 = (const float*)d_in[5];
    float* out = (float*)d_out;                // [N,128] f32

    const int N = in_sizes[0] / 128;
    const int E = in_sizes[1] / 2;
    const int* er = ei;        // sources (gathered)
    const int* ec = ei + E;    // destinations (scattered)

    char* ws = (char*)d_ws;
    size_t off = 0;
    auto alloc = [&](size_t b) { size_t o = off; off += (b + 255) & ~(size_t)255; return o; };
    size_t o_tot  = alloc((size_t)N * 4);
    size_t o_rp   = alloc((size_t)(N + 1) * 4);
    size_t o_dis  = alloc((size_t)N * 4);
    size_t o_bsum = alloc((size_t)1024 * 4);
    size_t o_rof  = alloc((size_t)1024 * 16 * 4);
    size_t o_srof = alloc((size_t)1024 * 16 * 4);
    size_t o_csr  = alloc((size_t)E * 2);
    size_t o_h    = alloc((size_t)N * 128 * 2);
    size_t o_prs  = alloc((size_t)(E + 1024) * 4);
    size_t o_srcp = alloc((size_t)(E + 1024) * 2);

    size_t rem = (ws_size > off + 4096) ? (ws_size - off - 4096) : 0;
    long long nc = (long long)(rem / (3 * (size_t)N));
    if (nc > 128) nc = 128;
    if (nc < 16) nc = 16;
    nc &= ~15LL;                              // NC multiple of 16 (chunk_scan needs NC%16==0)
    const int NC = (int)nc, NCD = NC / 2;
    const int NCP = NC * GP;                 // partition chunks
    const int GPD = NCP / NCD;               // = 16

    size_t o_pcol = alloc((size_t)NC * N * 2);
    size_t o_pdeg = alloc((size_t)NCD * N * 2);

    int*   tot  = (int*)(ws + o_tot);
    int*   rp   = (int*)(ws + o_rp);
    float* dis  = (float*)(ws + o_dis);
    int*   bsum = (int*)(ws + o_bsum);
    int*   rof  = (int*)(ws + o_rof);
    int*   srof = (int*)(ws + o_srof);
    u16*   csr  = (u16*)(ws + o_csr);
    u16*   h    = (u16*)(ws + o_h);
    u32*   prs  = (u32*)(ws + o_prs);
    u16*   srcp = (u16*)(ws + o_srcp);
    u16*   pcol = (u16*)(ws + o_pcol);
    u16*   pdeg = (u16*)(ws + o_pdeg);

    const int NR = (N + RS - 1) / RS;        // 7 for N=50000 (must be <= 15)
    const int cpb  = (E + NCP - 1) / NCP;
    const int nblk = (N + 255) / 256;        // 196 (<= 1024 required)
    const int csblk = (int)(((size_t)N * 8 + 255) / 256);

    partition_kernel<<<NCP, 256, 0, stream>>>(er, ec, prs, srcp, rof, srof, E, cpb, NR);
    colhist_kernel<<<dim3(NC, NR), 256, 0, stream>>>(prs, rof, pcol, N, cpb);
    deghist_kernel<<<dim3(NCD, NR), 256, 0, stream>>>(srcp, srof, pdeg, N, cpb, GPD);
    chunk_scan_kernel<<<csblk, 256, 0, stream>>>(pcol, pdeg, tot, dis, N, NC, NCD);
    bsum_kernel<<<nblk, 256, 0, stream>>>(tot, bsum, N);
    scan_bsum_kernel<<<1, 1024, 0, stream>>>(bsum, nblk);
    rowptr_kernel<<<nblk, 256, 0, stream>>>(tot, bsum, rp, N, E);
    fill_kernel<<<dim3(NC, NR), 256, 0, stream>>>(prs, rof, rp, pcol, csr, N, cpb);

    // layer 1: h' = dis.*bf16(x@W1) ; d_out = relu(agg(h') + b1)
    gemm_xw<<<(N + 63) / 64, 256, 0, stream>>>(x, W1, dis, h, N);
    agg_kernel<<<(N + 3) / 4, 256, 0, stream>>>(h, dis, rp, csr, b1, out, N, 1);

    // layer 2: h' = dis.*bf16(d_out@W2) ; d_out = agg(h') + b2
    gemm_xw<<<(N + 63) / 64, 256, 0, stream>>>(out, W2, dis, h, N);
    agg_kernel<<<(N + 3) / 4, 256, 0, stream>>>(h, dis, rp, csr, b2, out, N, 0);
}